// Round 4
// baseline (347.917 us; speedup 1.0000x reference)
//
#include <hip/hip_runtime.h>
#include <math.h>

#define N_NODES 100000
#define N_EDGES 2500000
#define N_GRAPHS 512
#define IN_DIM 14
#define HID 32
#define CAP 64        // per-node slot capacity; degree ~ Poisson(25), max ~55

// dst-buckets: bucket = dst >> 7 (128 nodes each)
#define BSHIFT 7
#define BNODES 128
#define NB 782        // ceil(100000/128)
#define NBP 784
#define NBANKS 8      // one bank per XCD (blockIdx % 8 == XCD round-robin)
#define SUBCAP 512    // mean 400 edges/(bucket,bank), ~5.6 sigma headroom
#define BCAP 4096     // NBANKS * SUBCAP
#define CHUNK 4096    // FEW blocks (611) -> long reservation runs -> low write amp
#define TB_BIN 512    // but 8 waves/block -> round-3-level TLP without more blocks
#define NBLK_E ((N_EDGES + CHUNK - 1) / CHUNK)   // 611
#define EPT (CHUNK / TB_BIN)                      // 8 edges per thread

#define GSTRIDE 8                        // 32B per cursor; bank-major keeps lines XCD-local
#define GCUR_N (NBP * NBANKS * GSTRIDE)  // 50176 ints = 200 KB

typedef unsigned int uint;
typedef unsigned short ushort;

__device__ inline float bflo(uint w) { return __uint_as_float(w << 16); }
__device__ inline float bfhi(uint w) { return __uint_as_float(w & 0xffff0000u); }
__device__ inline ushort f2bf(float f) {
    uint u = __float_as_uint(f);
    return (ushort)((u + 0x7fffu + ((u >> 16) & 1u)) >> 16);  // RNE
}

// ============ pass 1: 3-phase block-batched binning (XCD-local banks) =========
// Write amplification ∝ #blocks (each block = one reservation run per bucket;
// run boundaries make partial lines). So: 611 blocks (CHUNK=4096) for ~25 MB
// writes, and TLP from 512-thread blocks (8 waves) instead of more blocks.
// dst/src are single-use streams -> non-temporal, keep L2 for segment tails.
__global__ void bin_edges(const int* __restrict__ src, const int* __restrict__ dst,
                          int* __restrict__ gcur, int* __restrict__ binned) {
    __shared__ int scnt[NBP];
    __shared__ int sbase[NBP];
    __shared__ int soff[NBP];
    int t = threadIdx.x;
    for (int i = t; i < NBP; i += TB_BIN) { scnt[i] = 0; soff[i] = 0; }
    __syncthreads();
    int base = blockIdx.x * CHUNK;
    int bank = blockIdx.x & (NBANKS - 1);
    int dreg[EPT];                       // cache dst across phases (no re-read)
#pragma unroll
    for (int j = 0; j < EPT; ++j) {
        int e = base + j * TB_BIN + t;
        dreg[j] = (e < N_EDGES) ? __builtin_nontemporal_load(dst + e) : -1;
        if (dreg[j] >= 0) atomicAdd(&scnt[dreg[j] >> BSHIFT], 1);
    }
    __syncthreads();
    for (int b = t; b < NBP; b += TB_BIN) {
        int c = scnt[b];
        sbase[b] = (c > 0) ? atomicAdd(&gcur[(bank * NBP + b) * GSTRIDE], c) : 0;
    }
    __syncthreads();
#pragma unroll
    for (int j = 0; j < EPT; ++j) {
        int d = dreg[j];
        if (d >= 0) {
            int e = base + j * TB_BIN + t;
            int b = d >> BSHIFT;
            int s = __builtin_nontemporal_load(src + e);
            int pos = sbase[b] + atomicAdd(&soff[b], 1);
            if (pos < SUBCAP)
                binned[b * BCAP + bank * SUBCAP + pos] = (s << BSHIFT) | (d & (BNODES - 1));
        }
    }
}

// ============ pass 2: 128x64 slot tile in LDS (dummy-padded), line-granular out ==
__global__ void build_slots(const int* __restrict__ gcur, const int* __restrict__ binned,
                            int* __restrict__ deg, int* __restrict__ slots) {
    __shared__ int stile[BNODES * CAP];  // 32 KB
    __shared__ int sdeg[BNODES];
    int t = threadIdx.x;
    for (int i = t; i < BNODES * CAP; i += 256) stile[i] = N_NODES;  // dummy pad
    if (t < BNODES) sdeg[t] = 0;
    __syncthreads();
    int b = blockIdx.x;
#pragma unroll
    for (int k = 0; k < NBANKS; ++k) {
        int cnt = gcur[(k * NBP + b) * GSTRIDE]; if (cnt > SUBCAP) cnt = SUBCAP;
        const int* seg = binned + b * BCAP + k * SUBCAP;
        for (int i = t; i < cnt; i += 256) {
            int w = __builtin_nontemporal_load(seg + i);   // single-use stream
            int ld = w & (BNODES - 1), sn = w >> BSHIFT;
            int p = atomicAdd(&sdeg[ld], 1);
            if (p < CAP) stile[ld * CAP + p] = sn;
        }
    }
    __syncthreads();
    int nbase = b * BNODES;
    int rows = N_NODES - nbase; if (rows > BNODES) rows = BNODES;
    int r = t & 127, h = t >> 7;           // 2 threads per row
    if (r < rows) {
        int dv = sdeg[r]; if (dv > CAP) dv = CAP;
        if (h == 0) deg[nbase + r] = dv;
        int n4 = ((dv + 15) >> 4) << 2;    // int4s covering whole 64B lines (incl. pad)
        int4* drow = (int4*)(slots + (size_t)(nbase + r) * CAP);
        const int4* srow = (const int4*)(stile + r * CAP);
        for (int i = h; i < n4; i += 2) drow[i] = srow[i];
    }
}

// ============ layer-1 pre-GEMM: tmp(bf16) = x @ W_rel1; zero dummy rows ========
__global__ void gemm14(const float* __restrict__ h, const float* __restrict__ W,
                       ushort* __restrict__ out, ushort* __restrict__ zrow2) {
    __shared__ float sW[IN_DIM][HID];
    int t = threadIdx.x;
    for (int i = t; i < IN_DIM * HID; i += 256) sW[i / HID][i % HID] = W[i];
    if (blockIdx.x == 0) {   // zero dummy row N_NODES in both bf16 tables
        if (t < 4) ((uint4*)(out + (size_t)N_NODES * HID))[t] = make_uint4(0, 0, 0, 0);
        else if (t < 8) ((uint4*)(zrow2 + (size_t)N_NODES * HID))[t - 4] = make_uint4(0, 0, 0, 0);
    }
    __syncthreads();
    int idx = blockIdx.x * 256 + t;
    if (idx >= N_NODES * HID) return;
    int n = idx >> 5, o = idx & 31;
    const float* hr = h + (long)n * IN_DIM;
    float acc = 0.f;
#pragma unroll
    for (int k = 0; k < IN_DIM; ++k) acc += hr[k] * sW[k][o];
    out[idx] = f2bf(acc);
}

// ============ fused conv (R8 structure): 4 lanes/node, uint4 gathers ==========
// Slot words + deg are single-use streams (12.8 MB/layer) -> non-temporal loads
// keep L2 ways free for the 6.4 MB featb gather table (read ~25x per row).
template <bool MUL_REL, int K, bool ROOT_BF16>
__global__ void conv_fused(const int* __restrict__ deg, const int* __restrict__ slots,
                           const ushort* __restrict__ featb,  // (N+1) x 32 bf16 table
                           const void* __restrict__ root_in,  // N x K (bf16 or f32)
                           const float* __restrict__ Wrel,    // 32x32 (if MUL_REL)
                           const float* __restrict__ bias,    // 32
                           const float* __restrict__ Wroot,   // K x 32
                           ushort* __restrict__ outb) {       // (N+1) x 32 bf16
    __shared__ float sWrel[MUL_REL ? HID * HID : 1];
    __shared__ float sWroot[K * HID];
    __shared__ float sb[HID];
    int t = threadIdx.x;
    if (MUL_REL)
        for (int i = t; i < HID * HID; i += 256) sWrel[i] = Wrel[i];
    for (int i = t; i < K * HID; i += 256) sWroot[i] = Wroot[i];
    if (t < HID) sb[t] = bias[t];
    __syncthreads();

    int n = blockIdx.x * 64 + (t >> 2);
    if (n >= N_NODES) return;
    int q = t & 3;           // lane in 4-group: owns features q*8 .. q*8+7

    int dn = __builtin_nontemporal_load(deg + n); if (dn > CAP) dn = CAP;
    int rounds = (dn + 7) >> 3;
    const int* sl = slots + (size_t)n * CAP;
    int2 my[8];
#pragma unroll
    for (int r = 0; r < 8; ++r)
        if (r < rounds) {
            long w = __builtin_nontemporal_load((const long*)(sl + r * 8 + q * 2));
            my[r].x = (int)(w & 0xffffffffL);
            my[r].y = (int)(w >> 32);
        }

    float a[8] = {0.f, 0.f, 0.f, 0.f, 0.f, 0.f, 0.f, 0.f};
#pragma unroll
    for (int r = 0; r < 8; ++r) {
        if (r < rounds) {
#pragma unroll
            for (int j = 0; j < 8; ++j) {
                int c = __shfl((j & 1) ? my[r].y : my[r].x, j >> 1, 4);  // dummy row if padded
                uint4 v = *(const uint4*)(featb + (size_t)c * HID + q * 8);
                a[0] += bflo(v.x); a[1] += bfhi(v.x);
                a[2] += bflo(v.y); a[3] += bfhi(v.y);
                a[4] += bflo(v.z); a[5] += bfhi(v.z);
                a[6] += bflo(v.w); a[7] += bfhi(v.w);
            }
        }
    }

    float r8[8];
#pragma unroll
    for (int o = 0; o < 8; ++o) r8[o] = sb[q * 8 + o];

    if constexpr (MUL_REL) {
#pragma unroll
        for (int cl = 0; cl < 4; ++cl) {
#pragma unroll
            for (int j = 0; j < 8; ++j) {
                float av = __shfl(a[j], cl, 4);
                const float* w = &sWrel[(cl * 8 + j) * HID + q * 8];
#pragma unroll
                for (int o = 0; o < 8; ++o) r8[o] += av * w[o];
            }
        }
    } else {
#pragma unroll
        for (int o = 0; o < 8; ++o) r8[o] += a[o];
    }

    if constexpr (ROOT_BF16) {
        uint4 h4 = *(const uint4*)((const ushort*)root_in + (size_t)n * HID + q * 8);
        float hh[8] = {bflo(h4.x), bfhi(h4.x), bflo(h4.y), bfhi(h4.y),
                       bflo(h4.z), bfhi(h4.z), bflo(h4.w), bfhi(h4.w)};
#pragma unroll
        for (int cl = 0; cl < 4; ++cl) {
#pragma unroll
            for (int j = 0; j < 8; ++j) {
                float hv = __shfl(hh[j], cl, 4);
                const float* w = &sWroot[(cl * 8 + j) * HID + q * 8];
#pragma unroll
                for (int o = 0; o < 8; ++o) r8[o] += hv * w[o];
            }
        }
    } else {
        const float* hr = (const float*)root_in + (long)n * K;
#pragma unroll
        for (int k = 0; k < K; ++k) {
            float hv = hr[k];
            const float* w = &sWroot[k * HID + q * 8];
#pragma unroll
            for (int o = 0; o < 8; ++o) r8[o] += hv * w[o];
        }
    }

    uint pw[4];
#pragma unroll
    for (int m = 0; m < 4; ++m)
        pw[m] = (uint)f2bf(fmaxf(r8[2 * m], 0.f)) |
                ((uint)f2bf(fmaxf(r8[2 * m + 1], 0.f)) << 16);
    *(uint4*)(outb + (size_t)n * HID + q * 8) = make_uint4(pw[0], pw[1], pw[2], pw[3]);
}

// ============ sum pool per graph (batch sorted -> run-length accumulate) ======
#define POOL_NODES 128
__global__ void pool_sum(const ushort* __restrict__ h, const int* __restrict__ batch,
                         float* __restrict__ g) {
    __shared__ int sbatch[POOL_NODES];
    int t = threadIdx.x;
    int nbase = blockIdx.x * POOL_NODES;
    for (int i = t; i < POOL_NODES; i += 256) {
        int n = nbase + i;
        sbatch[i] = (n < N_NODES) ? batch[n] : -1;
    }
    __syncthreads();
    int f = t & 31;
    int c0 = (t >> 5) * 16;
    int curb = -1;
    float acc = 0.f;
    for (int j = 0; j < 16; ++j) {
        int li = c0 + j;
        int n = nbase + li;
        if (n >= N_NODES) break;
        int bid = sbatch[li];
        float v = bflo((uint)h[(size_t)n * HID + f]);
        if (bid != curb) {
            if (curb >= 0) atomicAdd(&g[curb * HID + f], acc);
            curb = bid;
            acc = 0.f;
        }
        acc += v;
    }
    if (curb >= 0) atomicAdd(&g[curb * HID + f], acc);
}

// ============ head: relu(g@W1+b1) @ W2 + b2 -> log_softmax (4 blocks) =========
__global__ void head(const float* __restrict__ g, const float* __restrict__ w1,
                     const float* __restrict__ b1, const float* __restrict__ w2,
                     const float* __restrict__ b2, float* __restrict__ out) {
    __shared__ float sW1[HID][HID];
    __shared__ float sW2[HID][2];
    __shared__ float sb1[HID];
    int t = threadIdx.x;  // 128 threads, one graph each; 4 blocks
    for (int i = t; i < HID * HID; i += 128) sW1[i / HID][i % HID] = w1[i];
    if (t < HID * 2) sW2[t / 2][t % 2] = w2[t];
    if (t < HID) sb1[t] = b1[t];
    __syncthreads();
    int gid = blockIdx.x * 128 + t;
    float gi[HID];
#pragma unroll
    for (int k = 0; k < HID; ++k) gi[k] = g[gid * HID + k];
    float l0 = b2[0], l1 = b2[1];
#pragma unroll
    for (int o = 0; o < HID; ++o) {
        float a = sb1[o];
#pragma unroll
        for (int k = 0; k < HID; ++k) a += gi[k] * sW1[k][o];
        a = fmaxf(a, 0.f);
        l0 += a * sW2[o][0];
        l1 += a * sW2[o][1];
    }
    float m = fmaxf(l0, l1);
    float lse = m + logf(expf(l0 - m) + expf(l1 - m));
    out[gid * 2 + 0] = l0 - lse;
    out[gid * 2 + 1] = l1 - lse;
}

extern "C" void kernel_launch(void* const* d_in, const int* in_sizes, int n_in,
                              void* d_out, int out_size, void* d_ws, size_t ws_size,
                              hipStream_t stream) {
    const float* x      = (const float*)d_in[0];
    const float* W_rel1 = (const float*)d_in[1];
    const float* b_rel1 = (const float*)d_in[2];
    const float* W_root1= (const float*)d_in[3];
    const float* W_rel  = (const float*)d_in[4];   // 4 x 32 x 32
    const float* b_rel  = (const float*)d_in[5];   // 4 x 32
    const float* W_root = (const float*)d_in[6];   // 4 x 32 x 32
    const float* lin1_w = (const float*)d_in[7];
    const float* lin1_b = (const float*)d_in[8];
    const float* lin2_w = (const float*)d_in[9];
    const float* lin2_b = (const float*)d_in[10];
    const int*   ei     = (const int*)d_in[11];    // [2, E]: src then dst
    const int*   batch  = (const int*)d_in[12];
    float* out = (float*)d_out;

    const int* src = ei;
    const int* dst = ei + N_EDGES;

    // workspace layout (16B alignment at every vector-accessed region)
    int*    gcur   = (int*)d_ws;                        // GCUR_N ints (200 KB)
    int*    binned = gcur + GCUR_N;                     // NB*BCAP ints (12.8 MB)
    int*    deg    = binned + NB * BCAP;                // N pad N+32
    int*    slots  = deg + N_NODES + 32;                // N * CAP (25.6 MB)
    ushort* B0b    = (ushort*)(slots + (size_t)N_NODES * CAP);  // (N+1)*32 bf16
    ushort* B1b    = B0b + (size_t)(N_NODES + 1) * HID;         // (N+1)*32 bf16
    float*  g      = (float*)(B1b + (size_t)(N_NODES + 1) * HID);  // 512*32 f32

    dim3 blk(256);
    dim3 grd_no((N_NODES * HID + 255) / 256);  // 12500
    dim3 grd_cv((N_NODES + 63) / 64);          // 1563
    dim3 grd_pl((N_NODES + POOL_NODES - 1) / POOL_NODES);

    // ---- two-pass slot-table build ----
    hipMemsetAsync(gcur, 0, GCUR_N * sizeof(int), stream);
    bin_edges<<<dim3(NBLK_E), dim3(TB_BIN), 0, stream>>>(src, dst, gcur, binned);
    build_slots<<<dim3(NB), blk, 0, stream>>>(gcur, binned, deg, slots);

    // ---- layer 1: tmp = x@W_rel1 (bf16, +zero dummy rows); h1 = relu(gather+root) --
    gemm14<<<grd_no, blk, 0, stream>>>(x, W_rel1, B0b, B1b);
    conv_fused<false, IN_DIM, false><<<grd_cv, blk, 0, stream>>>(
        deg, slots, B0b, (const void*)x, nullptr, b_rel1, W_root1, B1b);

    // ---- layers 2..5: h' = relu(gather(h)@W_rel + b + h@W_root) ----
    ushort* cur = B1b;
    ushort* nxt = B0b;
    for (int i = 0; i < 4; ++i) {
        conv_fused<true, HID, true><<<grd_cv, blk, 0, stream>>>(
            deg, slots, cur, (const void*)cur, W_rel + i * HID * HID,
            b_rel + i * HID, W_root + i * HID * HID, nxt);
        ushort* tswap = cur; cur = nxt; nxt = tswap;
    }
    // final h in `cur`

    // ---- sum pool + head ----
    hipMemsetAsync(g, 0, (size_t)N_GRAPHS * HID * sizeof(float), stream);
    pool_sum<<<grd_pl, blk, 0, stream>>>(cur, batch, g);
    head<<<dim3(4), dim3(128), 0, stream>>>(g, lin1_w, lin1_b, lin2_w, lin2_b, out);
}

// Round 6
// 341.167 us; speedup vs baseline: 1.0198x; 1.0198x over previous
//
#include <hip/hip_runtime.h>
#include <math.h>

#define N_NODES 100000
#define N_EDGES 2500000
#define N_GRAPHS 512
#define IN_DIM 14
#define HID 32
#define CAP 64        // per-node slot capacity; degree ~ Poisson(25), max ~55

// dst-buckets: bucket = dst >> 7 (128 nodes each)
#define BSHIFT 7
#define BNODES 128
#define NB 782        // ceil(100000/128)
#define NBP 784
#define NBANKS 8      // one bank per XCD (blockIdx % 8 == XCD round-robin)
#define SUBCAP 512    // mean 400 edges/(bucket,bank), ~5.6 sigma headroom
#define BCAP 4096     // NBANKS * SUBCAP
#define CHUNK 4096    // FEW blocks (611) -> long reservation runs -> low write amp
#define TB_BIN 512    // 8 waves/block for TLP without more blocks
#define NBLK_E ((N_EDGES + CHUNK - 1) / CHUNK)   // 611
#define EPT (CHUNK / TB_BIN)                      // 8 edges per thread

#define GSTRIDE 8                        // 32B per cursor; bank-major keeps lines XCD-local
#define GCUR_N (NBP * NBANKS * GSTRIDE)  // 50176 ints = 200 KB

typedef unsigned int uint;
typedef unsigned short ushort;
typedef float v2f __attribute__((ext_vector_type(2)));

__device__ inline float bflo(uint w) { return __uint_as_float(w << 16); }
__device__ inline float bfhi(uint w) { return __uint_as_float(w & 0xffff0000u); }
__device__ inline ushort f2bf(float f) {
    uint u = __float_as_uint(f);
    return (ushort)((u + 0x7fffu + ((u >> 16) & 1u)) >> 16);  // RNE
}

// ============ pass 1: rank-fused 2-phase binning (XCD-local banks) ============
// Phase-1 counting atomicAdd RETURNS the within-block rank -> second LDS atomic
// round deleted. Few blocks (611) keep reservation runs long (write amp ∝
// block count, round-3 lesson); TLP from 512-thread blocks.
__global__ void bin_edges(const int* __restrict__ src, const int* __restrict__ dst,
                          int* __restrict__ gcur, int* __restrict__ binned) {
    __shared__ int scnt[NBP];
    __shared__ int sbase[NBP];
    int t = threadIdx.x;
    for (int i = t; i < NBP; i += TB_BIN) scnt[i] = 0;
    __syncthreads();
    int base = blockIdx.x * CHUNK;
    int bank = blockIdx.x & (NBANKS - 1);
    int dreg[EPT];   // dst cached across phases
    int rreg[EPT];   // within-block rank per bucket (from returning atomic)
#pragma unroll
    for (int j = 0; j < EPT; ++j) {
        int e = base + j * TB_BIN + t;
        dreg[j] = (e < N_EDGES) ? __builtin_nontemporal_load(dst + e) : -1;
        rreg[j] = (dreg[j] >= 0) ? atomicAdd(&scnt[dreg[j] >> BSHIFT], 1) : 0;
    }
    __syncthreads();
    for (int b = t; b < NBP; b += TB_BIN) {
        int c = scnt[b];
        sbase[b] = (c > 0) ? atomicAdd(&gcur[(bank * NBP + b) * GSTRIDE], c) : 0;
    }
    __syncthreads();
#pragma unroll
    for (int j = 0; j < EPT; ++j) {
        int d = dreg[j];
        if (d >= 0) {
            int e = base + j * TB_BIN + t;
            int b = d >> BSHIFT;
            int s = __builtin_nontemporal_load(src + e);
            int pos = sbase[b] + rreg[j];
            if (pos < SUBCAP)
                binned[b * BCAP + bank * SUBCAP + pos] = (s << BSHIFT) | (d & (BNODES - 1));
        }
    }
}

// ============ pass 2: 128x64 slot tile in LDS (dummy-padded), line-granular out ==
__global__ void build_slots(const int* __restrict__ gcur, const int* __restrict__ binned,
                            int* __restrict__ deg, int* __restrict__ slots) {
    __shared__ int stile[BNODES * CAP];  // 32 KB
    __shared__ int sdeg[BNODES];
    int t = threadIdx.x;
    for (int i = t; i < BNODES * CAP; i += 256) stile[i] = N_NODES;  // dummy pad
    if (t < BNODES) sdeg[t] = 0;
    __syncthreads();
    int b = blockIdx.x;
#pragma unroll
    for (int k = 0; k < NBANKS; ++k) {
        int cnt = gcur[(k * NBP + b) * GSTRIDE]; if (cnt > SUBCAP) cnt = SUBCAP;
        const int* seg = binned + b * BCAP + k * SUBCAP;
        for (int i = t; i < cnt; i += 256) {
            int w = __builtin_nontemporal_load(seg + i);   // single-use stream
            int ld = w & (BNODES - 1), sn = w >> BSHIFT;
            int p = atomicAdd(&sdeg[ld], 1);
            if (p < CAP) stile[ld * CAP + p] = sn;
        }
    }
    __syncthreads();
    int nbase = b * BNODES;
    int rows = N_NODES - nbase; if (rows > BNODES) rows = BNODES;
    int r = t & 127, h = t >> 7;           // 2 threads per row
    if (r < rows) {
        int dv = sdeg[r]; if (dv > CAP) dv = CAP;
        if (h == 0) deg[nbase + r] = dv;
        int n4 = ((dv + 15) >> 4) << 2;    // int4s covering whole 64B lines (incl. pad)
        int4* drow = (int4*)(slots + (size_t)(nbase + r) * CAP);
        const int4* srow = (const int4*)(stile + r * CAP);
        for (int i = h; i < n4; i += 2) drow[i] = srow[i];
    }
}

// ============ layer-1 pre-GEMM: tmp(bf16) = x @ W_rel1; zero dummy rows ========
__global__ void gemm14(const float* __restrict__ h, const float* __restrict__ W,
                       ushort* __restrict__ out, ushort* __restrict__ zrow2,
                       uint2* __restrict__ f0, uint2* __restrict__ f1) {
    __shared__ float sW[IN_DIM][HID];
    int t = threadIdx.x;
    for (int i = t; i < IN_DIM * HID; i += 256) sW[i / HID][i % HID] = W[i];
    if (blockIdx.x == 0) {   // zero dummy row N_NODES in all gather tables
        if (t < 4) ((uint4*)(out + (size_t)N_NODES * HID))[t] = make_uint4(0, 0, 0, 0);
        else if (t < 8) ((uint4*)(zrow2 + (size_t)N_NODES * HID))[t - 4] = make_uint4(0, 0, 0, 0);
        else if (t < 12) f0[(size_t)N_NODES * 4 + (t - 8)] = make_uint2(0, 0);
        else if (t < 16) f1[(size_t)N_NODES * 4 + (t - 12)] = make_uint2(0, 0);
    }
    __syncthreads();
    int idx = blockIdx.x * 256 + t;
    if (idx >= N_NODES * HID) return;
    int n = idx >> 5, o = idx & 31;
    const float* hr = h + (long)n * IN_DIM;
    float acc = 0.f;
#pragma unroll
    for (int k = 0; k < IN_DIM; ++k) acc += hr[k] * sW[k][o];
    out[idx] = f2bf(acc);
}

// ============ fused conv (R8 structure): 4 lanes/node ==========================
// GBF8: gather table is bf8-e5m2 (32B/row, 3.2MB -> fits a 4MB XCD L2; halves
// gather bytes vs bf16). e5m2 max = 57344: NO saturation risk (round-5's e4m3
// clamped at 448 -> 5e5 error). Only the neighbor-agg path is quantized; root
// path and layer-1 table stay bf16/f32 -> output err ~100x under threshold.
// Every layer emits BOTH bf16 (root/pool) and bf8 (next gather) outputs.
template <bool MUL_REL, int K, bool ROOT_BF16, bool GBF8>
__global__ void conv_fused(const int* __restrict__ deg, const int* __restrict__ slots,
                           const void* __restrict__ gat,      // bf16 or bf8 table
                           const void* __restrict__ root_in,  // N x K (bf16 or f32)
                           const float* __restrict__ Wrel,    // 32x32 (if MUL_REL)
                           const float* __restrict__ bias,    // 32
                           const float* __restrict__ Wroot,   // K x 32
                           ushort* __restrict__ outb,         // (N+1) x 32 bf16
                           uint2* __restrict__ outf8) {       // (N+1) x 32 bf8
    __shared__ float sWrel[MUL_REL ? HID * HID : 1];
    __shared__ float sWroot[K * HID];
    __shared__ float sb[HID];
    int t = threadIdx.x;
    if (MUL_REL)
        for (int i = t; i < HID * HID; i += 256) sWrel[i] = Wrel[i];
    for (int i = t; i < K * HID; i += 256) sWroot[i] = Wroot[i];
    if (t < HID) sb[t] = bias[t];
    __syncthreads();

    int n = blockIdx.x * 64 + (t >> 2);
    if (n >= N_NODES) return;
    int q = t & 3;           // lane in 4-group: owns features q*8 .. q*8+7

    int dn = __builtin_nontemporal_load(deg + n); if (dn > CAP) dn = CAP;
    int rounds = (dn + 7) >> 3;
    const int* sl = slots + (size_t)n * CAP;
    int2 my[8];
#pragma unroll
    for (int r = 0; r < 8; ++r)
        if (r < rounds) {
            long w = __builtin_nontemporal_load((const long*)(sl + r * 8 + q * 2));
            my[r].x = (int)(w & 0xffffffffL);
            my[r].y = (int)(w >> 32);
        }

    float a[8] = {0.f, 0.f, 0.f, 0.f, 0.f, 0.f, 0.f, 0.f};
#pragma unroll
    for (int r = 0; r < 8; ++r) {
        if (r < rounds) {
#pragma unroll
            for (int j = 0; j < 8; ++j) {
                int c = __shfl((j & 1) ? my[r].y : my[r].x, j >> 1, 4);  // dummy row if padded
                if constexpr (GBF8) {
                    uint2 v = ((const uint2*)gat)[(size_t)c * 4 + q];
                    v2f p0 = __builtin_amdgcn_cvt_pk_f32_bf8(v.x, false);
                    v2f p1 = __builtin_amdgcn_cvt_pk_f32_bf8(v.x, true);
                    v2f p2 = __builtin_amdgcn_cvt_pk_f32_bf8(v.y, false);
                    v2f p3 = __builtin_amdgcn_cvt_pk_f32_bf8(v.y, true);
                    a[0] += p0.x; a[1] += p0.y; a[2] += p1.x; a[3] += p1.y;
                    a[4] += p2.x; a[5] += p2.y; a[6] += p3.x; a[7] += p3.y;
                } else {
                    uint4 v = *(const uint4*)((const ushort*)gat + (size_t)c * HID + q * 8);
                    a[0] += bflo(v.x); a[1] += bfhi(v.x);
                    a[2] += bflo(v.y); a[3] += bfhi(v.y);
                    a[4] += bflo(v.z); a[5] += bfhi(v.z);
                    a[6] += bflo(v.w); a[7] += bfhi(v.w);
                }
            }
        }
    }

    float r8[8];
#pragma unroll
    for (int o = 0; o < 8; ++o) r8[o] = sb[q * 8 + o];

    if constexpr (MUL_REL) {
#pragma unroll
        for (int cl = 0; cl < 4; ++cl) {
#pragma unroll
            for (int j = 0; j < 8; ++j) {
                float av = __shfl(a[j], cl, 4);
                const float* w = &sWrel[(cl * 8 + j) * HID + q * 8];
#pragma unroll
                for (int o = 0; o < 8; ++o) r8[o] += av * w[o];
            }
        }
    } else {
#pragma unroll
        for (int o = 0; o < 8; ++o) r8[o] += a[o];
    }

    if constexpr (ROOT_BF16) {
        uint4 h4 = *(const uint4*)((const ushort*)root_in + (size_t)n * HID + q * 8);
        float hh[8] = {bflo(h4.x), bfhi(h4.x), bflo(h4.y), bfhi(h4.y),
                       bflo(h4.z), bfhi(h4.z), bflo(h4.w), bfhi(h4.w)};
#pragma unroll
        for (int cl = 0; cl < 4; ++cl) {
#pragma unroll
            for (int j = 0; j < 8; ++j) {
                float hv = __shfl(hh[j], cl, 4);
                const float* w = &sWroot[(cl * 8 + j) * HID + q * 8];
#pragma unroll
                for (int o = 0; o < 8; ++o) r8[o] += hv * w[o];
            }
        }
    } else {
        const float* hr = (const float*)root_in + (long)n * K;
#pragma unroll
        for (int k = 0; k < K; ++k) {
            float hv = hr[k];
            const float* w = &sWroot[k * HID + q * 8];
#pragma unroll
            for (int o = 0; o < 8; ++o) r8[o] += hv * w[o];
        }
    }

    float v[8];
#pragma unroll
    for (int o = 0; o < 8; ++o) v[o] = fmaxf(r8[o], 0.f);

    uint pw[4];
#pragma unroll
    for (int m = 0; m < 4; ++m)
        pw[m] = (uint)f2bf(v[2 * m]) | ((uint)f2bf(v[2 * m + 1]) << 16);
    *(uint4*)(outb + (size_t)n * HID + q * 8) = make_uint4(pw[0], pw[1], pw[2], pw[3]);

    uint w0 = __builtin_amdgcn_cvt_pk_bf8_f32(v[0], v[1], 0u, false);
    w0 = __builtin_amdgcn_cvt_pk_bf8_f32(v[2], v[3], w0, true);
    uint w1 = __builtin_amdgcn_cvt_pk_bf8_f32(v[4], v[5], 0u, false);
    w1 = __builtin_amdgcn_cvt_pk_bf8_f32(v[6], v[7], w1, true);
    outf8[(size_t)n * 4 + q] = make_uint2(w0, w1);
}

// ============ sum pool per graph (batch sorted -> run-length accumulate) ======
#define POOL_NODES 128
__global__ void pool_sum(const ushort* __restrict__ h, const int* __restrict__ batch,
                         float* __restrict__ g) {
    __shared__ int sbatch[POOL_NODES];
    int t = threadIdx.x;
    int nbase = blockIdx.x * POOL_NODES;
    for (int i = t; i < POOL_NODES; i += 256) {
        int n = nbase + i;
        sbatch[i] = (n < N_NODES) ? batch[n] : -1;
    }
    __syncthreads();
    int f = t & 31;
    int c0 = (t >> 5) * 16;
    int curb = -1;
    float acc = 0.f;
    for (int j = 0; j < 16; ++j) {
        int li = c0 + j;
        int n = nbase + li;
        if (n >= N_NODES) break;
        int bid = sbatch[li];
        float v = bflo((uint)h[(size_t)n * HID + f]);
        if (bid != curb) {
            if (curb >= 0) atomicAdd(&g[curb * HID + f], acc);
            curb = bid;
            acc = 0.f;
        }
        acc += v;
    }
    if (curb >= 0) atomicAdd(&g[curb * HID + f], acc);
}

// ============ head: relu(g@W1+b1) @ W2 + b2 -> log_softmax (4 blocks) =========
__global__ void head(const float* __restrict__ g, const float* __restrict__ w1,
                     const float* __restrict__ b1, const float* __restrict__ w2,
                     const float* __restrict__ b2, float* __restrict__ out) {
    __shared__ float sW1[HID][HID];
    __shared__ float sW2[HID][2];
    __shared__ float sb1[HID];
    int t = threadIdx.x;  // 128 threads, one graph each; 4 blocks
    for (int i = t; i < HID * HID; i += 128) sW1[i / HID][i % HID] = w1[i];
    if (t < HID * 2) sW2[t / 2][t % 2] = w2[t];
    if (t < HID) sb1[t] = b1[t];
    __syncthreads();
    int gid = blockIdx.x * 128 + t;
    float gi[HID];
#pragma unroll
    for (int k = 0; k < HID; ++k) gi[k] = g[gid * HID + k];
    float l0 = b2[0], l1 = b2[1];
#pragma unroll
    for (int o = 0; o < HID; ++o) {
        float a = sb1[o];
#pragma unroll
        for (int k = 0; k < HID; ++k) a += gi[k] * sW1[k][o];
        a = fmaxf(a, 0.f);
        l0 += a * sW2[o][0];
        l1 += a * sW2[o][1];
    }
    float m = fmaxf(l0, l1);
    float lse = m + logf(expf(l0 - m) + expf(l1 - m));
    out[gid * 2 + 0] = l0 - lse;
    out[gid * 2 + 1] = l1 - lse;
}

extern "C" void kernel_launch(void* const* d_in, const int* in_sizes, int n_in,
                              void* d_out, int out_size, void* d_ws, size_t ws_size,
                              hipStream_t stream) {
    const float* x      = (const float*)d_in[0];
    const float* W_rel1 = (const float*)d_in[1];
    const float* b_rel1 = (const float*)d_in[2];
    const float* W_root1= (const float*)d_in[3];
    const float* W_rel  = (const float*)d_in[4];   // 4 x 32 x 32
    const float* b_rel  = (const float*)d_in[5];   // 4 x 32
    const float* W_root = (const float*)d_in[6];   // 4 x 32 x 32
    const float* lin1_w = (const float*)d_in[7];
    const float* lin1_b = (const float*)d_in[8];
    const float* lin2_w = (const float*)d_in[9];
    const float* lin2_b = (const float*)d_in[10];
    const int*   ei     = (const int*)d_in[11];    // [2, E]: src then dst
    const int*   batch  = (const int*)d_in[12];
    float* out = (float*)d_out;

    const int* src = ei;
    const int* dst = ei + N_EDGES;

    // workspace layout (16B alignment at every vector-accessed region)
    int*    gcur   = (int*)d_ws;                        // GCUR_N ints (200 KB)
    int*    binned = gcur + GCUR_N;                     // NB*BCAP ints (12.8 MB)
    int*    deg    = binned + NB * BCAP;                // N pad N+32
    int*    slots  = deg + N_NODES + 32;                // N * CAP (25.6 MB)
    ushort* B0b    = (ushort*)(slots + (size_t)N_NODES * CAP);  // (N+1)*32 bf16
    ushort* B1b    = B0b + (size_t)(N_NODES + 1) * HID;         // (N+1)*32 bf16
    float*  g      = (float*)(B1b + (size_t)(N_NODES + 1) * HID);  // 512*32 f32
    uint2*  F0     = (uint2*)(g + N_GRAPHS * HID);      // (N+1)*32 bf8 (3.2 MB)
    uint2*  F1     = F0 + (size_t)(N_NODES + 1) * 4;    // (N+1)*32 bf8 (3.2 MB)

    dim3 blk(256);
    dim3 grd_no((N_NODES * HID + 255) / 256);  // 12500
    dim3 grd_cv((N_NODES + 63) / 64);          // 1563
    dim3 grd_pl((N_NODES + POOL_NODES - 1) / POOL_NODES);

    // ---- two-pass slot-table build ----
    hipMemsetAsync(gcur, 0, GCUR_N * sizeof(int), stream);
    bin_edges<<<dim3(NBLK_E), dim3(TB_BIN), 0, stream>>>(src, dst, gcur, binned);
    build_slots<<<dim3(NB), blk, 0, stream>>>(gcur, binned, deg, slots);

    // ---- layer 1: tmp = x@W_rel1 (bf16, +zero dummy rows); h1 = relu(gather+root) --
    gemm14<<<grd_no, blk, 0, stream>>>(x, W_rel1, B0b, B1b, F0, F1);
    conv_fused<false, IN_DIM, false, false><<<grd_cv, blk, 0, stream>>>(
        deg, slots, (const void*)B0b, (const void*)x, nullptr, b_rel1, W_root1, B1b, F1);

    // ---- layers 2..5: h' = relu(gather_bf8(h)@W_rel + b + h@W_root) ----
    ushort* cur = B1b;  uint2* curf = F1;
    ushort* nxt = B0b;  uint2* nxtf = F0;
    for (int i = 0; i < 4; ++i) {
        conv_fused<true, HID, true, true><<<grd_cv, blk, 0, stream>>>(
            deg, slots, (const void*)curf, (const void*)cur, W_rel + i * HID * HID,
            b_rel + i * HID, W_root + i * HID * HID, nxt, nxtf);
        ushort* ts = cur; cur = nxt; nxt = ts;
        uint2*  tf = curf; curf = nxtf; nxtf = tf;
    }
    // final h in `cur`

    // ---- sum pool + head ----
    hipMemsetAsync(g, 0, (size_t)N_GRAPHS * HID * sizeof(float), stream);
    pool_sum<<<grd_pl, blk, 0, stream>>>(cur, batch, g);
    head<<<dim3(4), dim3(128), 0, stream>>>(g, lin1_w, lin1_b, lin2_w, lin2_b, out);
}